// Round 8
// baseline (245.067 us; speedup 1.0000x reference)
//
#include <hip/hip_runtime.h>
#include <hip/hip_bf16.h>
#include <stdint.h>

#define Bsz 4096
#define Dn  512
#define Kn  128
#define Pn  16
#define An  32
#define TB  16

typedef __attribute__((ext_vector_type(4))) float  floatx4;
typedef __attribute__((ext_vector_type(8))) short  shortx8;

// Module-scope scratch (d_ws unused — harness poison fills are unconditional).
__device__ unsigned short g_mu_bf[Kn * Dn];
__device__ unsigned short g_mu_t[Dn * Kn];
__device__ float          g_munorm[Kn];

__device__ __forceinline__ unsigned short f2bf(float x) {
    union { float f; uint32_t u; } v; v.f = x;
    uint32_t u = v.u;
    uint32_t r = (u + 0x7FFFu + ((u >> 16) & 1u)) >> 16;
    return (unsigned short)r;
}

// Sum over the 16 lanes of a DPP row (m = lane&15), pure VALU.
__device__ __forceinline__ float rowsum16(float x) {
    x += __int_as_float(__builtin_amdgcn_update_dpp(0, __float_as_int(x), 0xB1, 0xF, 0xF, false));
    x += __int_as_float(__builtin_amdgcn_update_dpp(0, __float_as_int(x), 0x4E, 0xF, 0xF, false));
    x += __int_as_float(__builtin_amdgcn_update_dpp(0, __float_as_int(x), 0x124, 0xF, 0xF, false));
    x += __int_as_float(__builtin_amdgcn_update_dpp(0, __float_as_int(x), 0x128, 0xF, 0xF, false));
    return x;
}

// ---------------- K1: mu = alpha @ W (bf16 + transposed) + ||mu_k||^2 ----------------
__global__ __launch_bounds__(256) void k_mu(const float* __restrict__ alpha,
                                            const float* __restrict__ W,
                                            float* __restrict__ out) {
    __shared__ float al[An];
    __shared__ float red[4];
    int k = blockIdx.x, t = threadIdx.x;
    if (k == 0 && t == 0) *out = 0.f;
    if (t < An) al[t] = alpha[k * An + t];
    __syncthreads();
    int d0 = t, d1 = t + 256;
    float a0 = 0.f, a1 = 0.f;
#pragma unroll
    for (int a = 0; a < An; ++a) {
        float av = al[a];
        a0 = fmaf(av, W[a * Dn + d0], a0);
        a1 = fmaf(av, W[a * Dn + d1], a1);
    }
    unsigned short h0 = f2bf(a0), h1 = f2bf(a1);
    g_mu_bf[k * Dn + d0] = h0;  g_mu_bf[k * Dn + d1] = h1;
    g_mu_t[d0 * Kn + k] = h0;   g_mu_t[d1 * Kn + k] = h1;
    float nrm = a0 * a0 + a1 * a1;
#pragma unroll
    for (int msk = 1; msk < 64; msk <<= 1) nrm += __shfl_xor(nrm, msk);
    if ((t & 63) == 0) red[t >> 6] = nrm;
    __syncthreads();
    if (t == 0) g_munorm[k] = red[0] + red[1] + red[2] + red[3];
}

// ---------------- K2 (fused): S/softmax/wGw prologue + probe trace ----------------
// 256 blocks x 1024 thr (16 waves), 1 block/CU. Block bt owns b-rows
// [bt*16, bt*16+16). mu staged ONCE into LDS (XOR-swizzled); the k_w work
// (S = theta@mu^T, softmax -> w, wGw, lossA) now runs IN-BLOCK against the
// staged mu (bit-identical bf16 inputs -> identical w bits vs the old k_w),
// eliminating the serial k_w dispatch (~8-10us) and the g_w round-trip.
// Probe loop: wave wv = probe, free-running, 6-deep v window (was 4; ~900cyc
// slack >= HBM latency), first window issued BEFORE the staging barrier.
__global__ __launch_bounds__(1024, 4) void k_probe(const float* __restrict__ thetas,
                                                   const int* __restrict__ v_int,
                                                   const int* __restrict__ Np,
                                                   float* __restrict__ out) {
    __shared__ __align__(16) unsigned short mu_l[Kn * Dn];  // 128 KB, swizzled
    __shared__ float S_l[TB][132];
    __shared__ float w_l[TB][132];
    __shared__ short wbf[TB][136];
    __shared__ float part8[8][TB];
    __shared__ float thn[TB];
    __shared__ float SwS[TB];
    __shared__ float partial[16];

    const int tid = threadIdx.x;
    const int lane = tid & 63;
    const int wv = tid >> 6;          // 0..15 = probe in the main loop
    const int m = lane & 15;
    const int q = lane >> 4;
    const int bt = blockIdx.x;        // 0..255
    const int r0 = bt * TB;

    const float Nf = (float)(*Np);
    const float temper = Nf / (Nf + 1.0f);
    const int swz = (m & 7) << 4;     // row&7 == m&7 for all rows used (k,16-aligned)

    // ---- stage mu into LDS, XOR-swizzled: byte = row*1024 + (off ^ ((row&7)<<4)) ----
    {
        const int4* src = (const int4*)g_mu_bf;
#pragma unroll
        for (int i = 0; i < 8; ++i) {
            int c = i * 1024 + tid;                 // 16B chunk id, 8192 total
            int row = c >> 6;                        // 64 chunks per 1 KB row
            int off = (c & 63) * 16;
            int4 val = src[c];
            *(int4*)((char*)mu_l + row * 1024 + (off ^ ((row & 7) << 4))) = val;
        }
    }

    // ---- issue 6-deep v window BEFORE the barrier (HBM streams during staging;
    //      __syncthreads drains vmcnt(0), so values are resident through prologue) ----
    const size_t PB = (size_t)Bsz * Dn;
    const char* vg = (const char*)(v_int + (size_t)wv * PB + (size_t)(r0 + m) * Dn) + q * 32;
    int4 vb[6][2];
#pragma unroll
    for (int c = 0; c < 6; ++c) {
        vb[c][0] = *(const int4*)(vg + c * 128);
        vb[c][1] = *(const int4*)(vg + c * 128 + 16);
    }
    __syncthreads();

    // ---- S = theta @ mu^T (waves 0..7; wave wv owns k-cols wv*16..+16).
    //      A-frags built from global theta (32 KB tile, L1-served); thn for free. ----
    if (wv < 8) {
        const float* tg = thetas + (size_t)(r0 + m) * Dn + q * 8;
        floatx4 acc = {0.f, 0.f, 0.f, 0.f};
        float tn = 0.f;
#pragma unroll
        for (int dc = 0; dc < 16; ++dc) {
            float4 f0 = *(const float4*)(tg + dc * 32);
            float4 f1 = *(const float4*)(tg + dc * 32 + 4);
            tn += f0.x * f0.x + f0.y * f0.y + f0.z * f0.z + f0.w * f0.w
                + f1.x * f1.x + f1.y * f1.y + f1.z * f1.z + f1.w * f1.w;
            union { uint32_t u[4]; shortx8 s; } af;
            af.u[0] = (uint32_t)f2bf(f0.x) | ((uint32_t)f2bf(f0.y) << 16);
            af.u[1] = (uint32_t)f2bf(f0.z) | ((uint32_t)f2bf(f0.w) << 16);
            af.u[2] = (uint32_t)f2bf(f1.x) | ((uint32_t)f2bf(f1.y) << 16);
            af.u[3] = (uint32_t)f2bf(f1.z) | ((uint32_t)f2bf(f1.w) << 16);
            shortx8 bf = *(const shortx8*)((const char*)mu_l
                              + (wv * 16 + m) * 1024 + ((dc * 64 + q * 16) ^ swz));
            acc = __builtin_amdgcn_mfma_f32_16x16x32_bf16(af.s, bf, acc, 0, 0, 0);
        }
#pragma unroll
        for (int i = 0; i < 4; ++i) S_l[q * 4 + i][wv * 16 + m] = acc[i];
        tn += __shfl_xor(tn, 16);
        tn += __shfl_xor(tn, 32);
        if (wv == 0 && q == 0) thn[m] = tn;
    }
    __syncthreads();

    // ---- softmax over k (32 threads per b-row) -> w_l (f32) + wbf (bf16) ----
    if (tid < 512) {
        const int b = tid >> 5, s = tid & 31;
        float l[4];
        float mx = -3.4e38f;
        float tnb = thn[b];
#pragma unroll
        for (int j = 0; j < 4; ++j) {
            int k = s + 32 * j;
            l[j] = -0.5f * (tnb - 2.f * S_l[b][k] + g_munorm[k]);
            mx = fmaxf(mx, l[j]);
        }
#pragma unroll
        for (int msk = 1; msk < 32; msk <<= 1) mx = fmaxf(mx, __shfl_xor(mx, msk));
        float se = 0.f, ses = 0.f;
        float e[4];
#pragma unroll
        for (int j = 0; j < 4; ++j) {
            int k = s + 32 * j;
            e[j] = __expf(l[j] - mx);
            se += e[j];
            ses += e[j] * S_l[b][k];
        }
#pragma unroll
        for (int msk = 1; msk < 32; msk <<= 1) { se += __shfl_xor(se, msk); ses += __shfl_xor(ses, msk); }
        float inv = 1.f / se;
#pragma unroll
        for (int j = 0; j < 4; ++j) {
            int k = s + 32 * j;
            float wvv = e[j] * inv;
            w_l[b][k] = wvv;
            wbf[b][k] = (short)f2bf(wvv);
        }
        if (s == 0) SwS[b] = ses * inv;
    }
    __syncthreads();

    // ---- wGw = ||w @ mu||^2 (waves 0..7; B-frags from g_mu_t, L2-resident) ----
    if (wv < 8) {
        float sg[4] = {0.f, 0.f, 0.f, 0.f};
#pragma unroll
        for (int ct = 0; ct < 4; ++ct) {
            const unsigned short* mt = g_mu_t + (size_t)(wv * 64 + ct * 16 + m) * Kn + q * 8;
            floatx4 acc = {0.f, 0.f, 0.f, 0.f};
#pragma unroll
            for (int kc = 0; kc < 4; ++kc) {
                shortx8 a = *(const shortx8*)&wbf[m][kc * 32 + q * 8];
                shortx8 bfr = *(const shortx8*)(mt + kc * 32);
                acc = __builtin_amdgcn_mfma_f32_16x16x32_bf16(a, bfr, acc, 0, 0, 0);
            }
#pragma unroll
            for (int i = 0; i < 4; ++i) sg[i] += acc[i] * acc[i];
        }
#pragma unroll
        for (int i = 0; i < 4; ++i) sg[i] = rowsum16(sg[i]);
        if (m == 0) {
#pragma unroll
            for (int i = 0; i < 4; ++i) part8[wv][q * 4 + i] = sg[i];
        }
    }
    __syncthreads();

    if (tid < TB) {
        float wGw = 0.f;
#pragma unroll
        for (int w8 = 0; w8 < 8; ++w8) wGw += part8[w8][tid];
        float res = 0.5f * temper * temper * (wGw - 2.f * SwS[tid] + thn[tid])
                    - temper * (float)Dn;
#pragma unroll
        for (int msk = 1; msk < 16; msk <<= 1) res += __shfl_xor(res, msk);
        if (tid == 0) atomicAdd(out, res * (1.0f / (float)Bsz));
    }

    // ---- probe loop: wave wv = probe, free-running, 6-deep rolling window ----
    floatx4 acc[8];
#pragma unroll
    for (int kt = 0; kt < 8; ++kt) acc[kt] = (floatx4){0.f, 0.f, 0.f, 0.f};

#pragma unroll
    for (int dc = 0; dc < 16; ++dc) {
        int4 w0 = vb[dc % 6][0], w1 = vb[dc % 6][1];
        if (dc < 10) {
            vb[dc % 6][0] = *(const int4*)(vg + (dc + 6) * 128);
            vb[dc % 6][1] = *(const int4*)(vg + (dc + 6) * 128 + 16);
        }
        // bf16(2v-1): v=1 -> 0x3F80, v=0 -> 0xBF80 == 0xBF80 ^ (v<<15)
        union { uint32_t u[4]; shortx8 s; } af;
        af.u[0] = 0xBF80BF80u ^ ((uint32_t)w0.x << 15) ^ ((uint32_t)w0.y << 31);
        af.u[1] = 0xBF80BF80u ^ ((uint32_t)w0.z << 15) ^ ((uint32_t)w0.w << 31);
        af.u[2] = 0xBF80BF80u ^ ((uint32_t)w1.x << 15) ^ ((uint32_t)w1.y << 31);
        af.u[3] = 0xBF80BF80u ^ ((uint32_t)w1.z << 15) ^ ((uint32_t)w1.w << 31);
        const int boff = dc * 64 + q * 16;
#pragma unroll
        for (int kt = 0; kt < 8; ++kt) {
            shortx8 bf = *(const shortx8*)((const char*)mu_l
                              + (kt * 16 + m) * 1024 + (boff ^ swz));
            acc[kt] = __builtin_amdgcn_mfma_f32_16x16x32_bf16(af.s, bf, acc[kt], 0, 0, 0);
        }
    }

    // ---- epilogue: s1 = sum_k w*T^2, s2 = sum_k w*T per b-row ----
    float contrib = 0.f;
#pragma unroll
    for (int i = 0; i < 4; ++i) {
        float s1 = 0.f, s2 = 0.f;
#pragma unroll
        for (int kt = 0; kt < 8; ++kt) {
            float T = acc[kt][i];
            float ww = w_l[q * 4 + i][kt * 16 + m];
            s1 = fmaf(ww * T, T, s1);
            s2 = fmaf(ww, T, s2);
        }
        s1 = rowsum16(s1);
        s2 = rowsum16(s2);
        contrib += s1 - s2 * s2;
    }
    if (m != 0) contrib = 0.f;        // rowsum16 replicated across m-lanes
    contrib += __shfl_xor(contrib, 16);
    contrib += __shfl_xor(contrib, 32);
    if (lane == 0) partial[wv] = contrib;
    __syncthreads();
    if (tid == 0) {
        float t = 0.f;
#pragma unroll
        for (int i = 0; i < 16; ++i) t += partial[i];
        atomicAdd(out, t * temper * (1.0f / (float)Pn) * (1.0f / (float)Bsz));
    }
}

extern "C" void kernel_launch(void* const* d_in, const int* in_sizes, int n_in,
                              void* d_out, int out_size, void* d_ws, size_t ws_size,
                              hipStream_t stream) {
    const float* thetas = (const float*)d_in[0];
    const float* alpha  = (const float*)d_in[1];
    const float* W      = (const float*)d_in[2];
    const int*   v_int  = (const int*)d_in[3];
    const int*   Np     = (const int*)d_in[4];
    (void)d_ws; (void)ws_size;

    float* out = (float*)d_out;
    k_mu   <<<dim3(Kn),  dim3(256),  0, stream>>>(alpha, W, out);
    k_probe<<<dim3(256), dim3(1024), 0, stream>>>(thetas, v_int, Np, out);
}